// Round 6
// baseline (102.367 us; speedup 1.0000x reference)
//
#include <hip/hip_runtime.h>

typedef unsigned short u16;
typedef unsigned int u32;
typedef float f32x4 __attribute__((ext_vector_type(4)));
typedef short bf16x8 __attribute__((ext_vector_type(8)));

#define AS1 __attribute__((address_space(1)))
#define AS3 __attribute__((address_space(3)))

__device__ __forceinline__ void g2l16(const void* g, void* l) {
  __builtin_amdgcn_global_load_lds((const AS1 void*)g, (AS3 void*)l, 16, 0, 0);
}

__device__ __forceinline__ u32 bfr(float f) {
  u32 u = __float_as_uint(f);
  return (u + 0x7fffu + ((u >> 16) & 1u)) >> 16;
}

#define PI_F 3.14159265358979323846f

// ---------------- convert x (f32 -> bf16), 8 elems/thread ----------------
__global__ __launch_bounds__(256) void cvt_x(const float* __restrict__ x, u16* __restrict__ xb) {
  long t = (long)blockIdx.x * blockDim.x + threadIdx.x;
  const float4 a = ((const float4*)x)[t * 2 + 0];
  const float4 b = ((const float4*)x)[t * 2 + 1];
  uint4 o;
  o.x = bfr(a.x) | (bfr(a.y) << 16);
  o.y = bfr(a.z) | (bfr(a.w) << 16);
  o.z = bfr(b.x) | (bfr(b.y) << 16);
  o.w = bfr(b.z) | (bfr(b.w) << 16);
  ((uint4*)xb)[t] = o;
}

// ---------------- W1 [1024][2048] f32 -> w1t [2048][1024] bf16 -----------
__global__ __launch_bounds__(256) void cvt_w1t(const float* __restrict__ W1, u16* __restrict__ w1t) {
  __shared__ u16 T[64][65];
  int bid = blockIdx.x;
  int kt = (bid & 15) << 6;
  int nt = (bid >> 4) << 6;
  int tid = threadIdx.x;
  #pragma unroll
  for (int i = 0; i < 16; ++i) {
    int e = i * 256 + tid;
    int r = e >> 6, c = e & 63;
    T[r][c] = (u16)bfr(W1[(long)(kt + r) * 2048 + nt + c]);
  }
  __syncthreads();
  #pragma unroll
  for (int i = 0; i < 16; ++i) {
    int e = i * 256 + tid;
    int n = e >> 6, k = e & 63;
    w1t[(long)(nt + n) * 1024 + kt + k] = T[k][n];
  }
}

// ---------------- W2 [2048][16] f32 -> w2t [16][2048] bf16 ---------------
__global__ __launch_bounds__(256) void cvt_w2t(const float* __restrict__ W2, u16* __restrict__ w2t) {
  int idx = blockIdx.x * 256 + threadIdx.x;
  int k = idx >> 4, q = idx & 15;
  w2t[q * 2048 + k] = (u16)bfr(W2[idx]);
}

// ==================== fused GEMM1 + E-partial =============================
// 128(M)x256(N) tile, BK=32, 4 waves (1Mx4N, per-wave 128x64), triple-
// buffered 72 KB LDS -> 2 blocks/CU for cross-block MFMA/LDS overlap.
// Stage t+2 during tile t, gate vmcnt(6). 64-B-row swizzle:
// chunk ^= (row>>1)&3 (16-B chunks), involution on store-src & read.
// Epilogue: P=relu(acc+b1)->bf16 in LDS, E-MFMA vs w2t, wn-reduce,
// store Ep[tn][row][q] f32.
__global__ __launch_bounds__(256, 2) void gemm1_fused(
    const u16* __restrict__ xb, const u16* __restrict__ w1t,
    const float* __restrict__ b1, const u16* __restrict__ w2t,
    float* __restrict__ Ep) {
  __shared__ __align__(16) char LDS[73728];   // 3 slots x (8 KB A + 16 KB B)

  // XCD swizzle: 1024 blocks = 8 xcds x 128; tn fastest (w1t L2-resident)
  const int xcd = blockIdx.x & 7;
  const int idx = blockIdx.x >> 3;           // 0..127
  const int tm = xcd * 16 + (idx >> 3);      // 0..127
  const int tn = idx & 7;                    // 0..7
  const int tid = threadIdx.x;
  const int lane = tid & 63;
  const int wn = tid >> 6;                   // 0..3 (wave id = N slice)
  const int l15 = lane & 15;
  const int cg = lane >> 4;                  // 0..3
  const int rk = ((l15 >> 1) & 3) << 4;      // read-side swizzle XOR
  const int cbr = (cg << 4) ^ rk;            // fragment chunk byte (swizzled)
  const int pkey = (l15 & 7) << 4;           // epilogue P swizzle (128-B rows)

  const u16* Ag = xb + (long)tm * 128 * 1024;
  const u16* Bg = w1t + (long)tn * 256 * 1024;

  char* s0 = LDS;                 // tile j
  char* s1 = LDS + 24576;         // tile j+1
  char* s2 = LDS + 49152;         // tile j+2 (staging target)

  bf16x8 a[8], b[4];
  f32x4 acc[8][4] = {};

// stage A tile t (128 rows x 32 K) into slot: linear LDS dest,
// inverse-swizzled global source (chunk ^ (row>>1)&3 within 64-B row)
#define STGA(sl, t) do {                                                     \
    _Pragma("unroll")                                                        \
    for (int rr = 0; rr < 2; ++rr) {                                         \
      int off = rr * 4096 + tid * 16;                                        \
      int row = off >> 6;                                                    \
      int ch = (off >> 4) & 3;                                               \
      int cb = ((ch ^ ((row >> 1) & 3)) << 4);                               \
      g2l16((const char*)Ag + (long)row * 2048 + (t) * 64 + cb,              \
            (sl) + off);                                                     \
    } } while (0)

// stage B tile t (256 rows x 32 K) into slot+8192
#define STGB(sl, t) do {                                                     \
    _Pragma("unroll")                                                        \
    for (int rr = 0; rr < 4; ++rr) {                                         \
      int off = rr * 4096 + tid * 16;                                        \
      int row = off >> 6;                                                    \
      int ch = (off >> 4) & 3;                                               \
      int cb = ((ch ^ ((row >> 1) & 3)) << 4);                               \
      g2l16((const char*)Bg + (long)row * 2048 + (t) * 64 + cb,              \
            (sl) + 8192 + off);                                              \
    } } while (0)

#define RDALL(sl) do {                                                       \
    _Pragma("unroll")                                                        \
    for (int m = 0; m < 8; ++m)                                              \
      a[m] = *(const bf16x8*)((sl) + m * 1024 + l15 * 64 + cbr);             \
    _Pragma("unroll")                                                        \
    for (int n = 0; n < 4; ++n)                                              \
      b[n] = *(const bf16x8*)((sl) + 8192 + wn * 4096 + n * 1024 +           \
                              l15 * 64 + cbr);                               \
  } while (0)

#define MM32() do {                                                          \
    __builtin_amdgcn_s_setprio(1);                                           \
    _Pragma("unroll")                                                        \
    for (int m = 0; m < 8; ++m)                                              \
      _Pragma("unroll")                                                      \
      for (int n = 0; n < 4; ++n)                                            \
        acc[m][n] = __builtin_amdgcn_mfma_f32_16x16x32_bf16(                 \
            a[m], b[n], acc[m][n], 0, 0, 0);                                 \
    __builtin_amdgcn_s_setprio(0);                                           \
  } while (0)

#define SB  __builtin_amdgcn_sched_barrier(0)
#define BAR __builtin_amdgcn_s_barrier()
#define GATE(n) do { SB;                                                     \
    asm volatile("s_waitcnt vmcnt(" #n ")" ::: "memory");                    \
    BAR; SB; } while (0)

  // prologue: stage t0 -> slot0 (6 loads), t1 -> slot1 (6 loads)
  STGA(s0, 0); STGB(s0, 0);
  STGA(s1, 1); STGB(s1, 1);
  GATE(6);                               // t0 landed, t1 in flight

  #pragma unroll 1
  for (int j = 0; j < 32; ++j) {
    const bool pf = (j < 30);
    if (pf) { STGA(s2, j + 2); STGB(s2, j + 2); }   // issue early
    RDALL(s0);
    MM32();
    if (pf)            GATE(6);
    else if (j == 30)  GATE(0);
    // j == 31: nothing outstanding; epilogue sync below
    char* rot = s0; s0 = s1; s1 = s2; s2 = rot;
  }
  __syncthreads();   // all waves' ds_reads done before LDS reuse

  // ============== epilogue: E-partial = relu(acc+b1) @ W2slice ===========
  // P per-wave region (16 KB), rows 128 x 64 cols bf16, 128-B-row swizzle.
  char* Pw = LDS + wn * 16384;
  #pragma unroll
  for (int n = 0; n < 4; ++n) {
    const float bias = b1[tn * 256 + wn * 64 + n * 16 + l15];
    #pragma unroll
    for (int mr = 0; mr < 8; ++mr) {
      #pragma unroll
      for (int jj = 0; jj < 4; ++jj) {
        int row = mr * 16 + cg * 4 + jj;   // 0..127
        float v = acc[mr][n][jj] + bias;
        v = v > 0.f ? v : 0.f;
        int cbyte = ((n * 16 + l15) * 2) ^ ((row & 7) << 4);
        *(u16*)(Pw + row * 128 + cbyte) = (u16)bfr(v);
      }
    }
  }
  // B-frags: W2^T[q = l15][k within this wave's 64-col slice]
  const u16* w2p = w2t + l15 * 2048 + tn * 256 + wn * 64;
  bf16x8 bw0 = *(const bf16x8*)(w2p + cg * 8);
  bf16x8 bw1 = *(const bf16x8*)(w2p + 32 + cg * 8);
  f32x4 acc2[8];
  #pragma unroll
  for (int mf = 0; mf < 8; ++mf) {
    bf16x8 a0 = *(const bf16x8*)(Pw + (mf * 16 + l15) * 128 + ((cg * 16) ^ pkey));
    bf16x8 a1 = *(const bf16x8*)(Pw + (mf * 16 + l15) * 128 + ((64 + cg * 16) ^ pkey));
    f32x4 z = {0.f, 0.f, 0.f, 0.f};
    z = __builtin_amdgcn_mfma_f32_16x16x32_bf16(a0, bw0, z, 0, 0, 0);
    z = __builtin_amdgcn_mfma_f32_16x16x32_bf16(a1, bw1, z, 0, 0, 0);
    acc2[mf] = z;
  }
  __syncthreads();   // all P reads done before Ew overwrites LDS
  // Ew[128 rows][16 q x 4 wn (+4 pad)] f32, stride 68
  float* Ew = (float*)LDS;
  #pragma unroll
  for (int mf = 0; mf < 8; ++mf)
    #pragma unroll
    for (int rg = 0; rg < 4; ++rg)
      Ew[(mf * 16 + cg * 4 + rg) * 68 + l15 * 4 + wn] = acc2[mf][rg];
  __syncthreads();
  // reduce over wn, store Ep[tn][tm*128 + row][q]
  #pragma unroll
  for (int c = tid; c < 2048; c += 256) {
    int row = c >> 4, q = c & 15;
    const float* e4 = &Ew[row * 68 + q * 4];
    float s = e4[0] + e4[1] + e4[2] + e4[3];
    Ep[(long)tn * (16384 * 16) + (long)(tm * 128 + row) * 16 + q] = s;
  }
#undef STGA
#undef STGB
#undef RDALL
#undef MM32
#undef SB
#undef BAR
#undef GATE
}

// ---------------- final: sum Ep, +b2, tanh, sin, VQC, sigmoid -------------
__global__ __launch_bounds__(256) void vqc_final(
    const float* __restrict__ Ep, const float* __restrict__ b2,
    const float* __restrict__ vqc, const float* __restrict__ Wd,
    const float* __restrict__ bd, float* __restrict__ out) {
  const int tid = threadIdx.x;
  const int lane = tid & 63;
  const int wave = tid >> 6;
  const int q = lane & 15;
  const int g = lane >> 4;
  const int row = blockIdx.x * 16 + wave * 4 + g;

  float e = 0.f;
  #pragma unroll
  for (int p = 0; p < 8; ++p)
    e += Ep[(long)p * (16384 * 16) + (long)row * 16 + q];

  float ct[6], sp[6];
  #pragma unroll
  for (int L = 0; L < 6; ++L) {
    float th = vqc[(L * 16 + q) * 2 + 0];
    float ph = vqc[(L * 16 + q) * 2 + 1];
    ct[L] = __cosf(th);
    sp[L] = __sinf(th) * __cosf(ph);
  }
  float s = __sinf(tanhf(e + b2[q]) * PI_F);
  #pragma unroll
  for (int L = 0; L < 6; ++L) {
    s = ct[L] * s + sp[L];
    if (L < 5) {
      float ps = __shfl_xor(s, 1, 64);
      s = (q & 1) ? (0.1f * ps + 0.9f * s) : s;
    }
  }
  float p = s * Wd[q];
  p += __shfl_xor(p, 1, 64);
  p += __shfl_xor(p, 2, 64);
  p += __shfl_xor(p, 4, 64);
  p += __shfl_xor(p, 8, 64);
  if (q == 0) out[row] = 1.f / (1.f + __expf(-(p + bd[0])));
}

// ---------------- fp32 fallback (ws too small): slow but correct ---------
__global__ __launch_bounds__(256) void fallback(
    const float* __restrict__ x, const float* __restrict__ W1,
    const float* __restrict__ b1, const float* __restrict__ W2,
    const float* __restrict__ b2, const float* __restrict__ vqc,
    const float* __restrict__ Wd, const float* __restrict__ bd,
    float* __restrict__ out) {
  __shared__ float xs[4][1024];
  __shared__ float E[4][16];
  const int bid = blockIdx.x;
  const int tid = threadIdx.x;
  const int r0 = bid * 4;
  for (int i = tid; i < 4 * 1024; i += 256)
    xs[i >> 10][i & 1023] = x[(long)(r0 + (i >> 10)) * 1024 + (i & 1023)];
  if (tid < 64) ((float*)E)[tid] = 0.f;
  __syncthreads();
  float pE[4][16];
  #pragma unroll
  for (int r = 0; r < 4; ++r)
    #pragma unroll
    for (int qq = 0; qq < 16; ++qq) pE[r][qq] = 0.f;
  for (int jj = 0; jj < 8; ++jj) {
    int j = jj * 256 + tid;
    float h0 = 0, h1 = 0, h2 = 0, h3 = 0;
    for (int k = 0; k < 1024; ++k) {
      float w = W1[(long)k * 2048 + j];
      h0 += xs[0][k] * w; h1 += xs[1][k] * w; h2 += xs[2][k] * w; h3 += xs[3][k] * w;
    }
    float hh[4] = {h0, h1, h2, h3};
    #pragma unroll
    for (int r = 0; r < 4; ++r) {
      float hr = hh[r] + b1[j];
      hr = hr > 0.f ? hr : 0.f;
      #pragma unroll
      for (int qq = 0; qq < 16; ++qq) pE[r][qq] += hr * W2[j * 16 + qq];
    }
  }
  #pragma unroll
  for (int r = 0; r < 4; ++r)
    #pragma unroll
    for (int qq = 0; qq < 16; ++qq) atomicAdd(&E[r][qq], pE[r][qq]);
  __syncthreads();
  if (tid < 4) {
    int r = tid;
    float s[16];
    #pragma unroll
    for (int qq = 0; qq < 16; ++qq)
      s[qq] = __sinf(tanhf(E[r][qq] + b2[qq]) * PI_F);
    #pragma unroll
    for (int L = 0; L < 6; ++L) {
      #pragma unroll
      for (int qq = 0; qq < 16; ++qq)
        s[qq] = __cosf(vqc[(L * 16 + qq) * 2]) * s[qq] +
                __sinf(vqc[(L * 16 + qq) * 2]) * __cosf(vqc[(L * 16 + qq) * 2 + 1]);
      if (L < 5)
        #pragma unroll
        for (int qq = 1; qq < 16; qq += 2) s[qq] = 0.1f * s[qq - 1] + 0.9f * s[qq];
    }
    float z = bd[0];
    #pragma unroll
    for (int qq = 0; qq < 16; ++qq) z += s[qq] * Wd[qq];
    out[r0 + r] = 1.f / (1.f + __expf(-z));
  }
}

extern "C" void kernel_launch(void* const* d_in, const int* in_sizes, int n_in,
                              void* d_out, int out_size, void* d_ws, size_t ws_size,
                              hipStream_t stream) {
  const float* x   = (const float*)d_in[0];
  const float* W1  = (const float*)d_in[1];
  const float* b1  = (const float*)d_in[2];
  const float* W2  = (const float*)d_in[3];
  const float* b2  = (const float*)d_in[4];
  const float* vqc = (const float*)d_in[5];
  const float* Wd  = (const float*)d_in[6];
  const float* bd  = (const float*)d_in[7];
  float* out = (float*)d_out;

  const size_t OFF_XB  = 0;                         // 33554432
  const size_t OFF_W1T = 33554432;                  // +4194304
  const size_t OFF_W2T = 37748736;                  // +65536
  const size_t OFF_EP  = 37814272;                  // +8388608
  const size_t NEED    = 46202880;

  if (ws_size < NEED) {
    fallback<<<4096, 256, 0, stream>>>(x, W1, b1, W2, b2, vqc, Wd, bd, out);
    return;
  }
  u16*   xb  = (u16*)((char*)d_ws + OFF_XB);
  u16*   w1t = (u16*)((char*)d_ws + OFF_W1T);
  u16*   w2t = (u16*)((char*)d_ws + OFF_W2T);
  float* Ep  = (float*)((char*)d_ws + OFF_EP);

  cvt_x<<<8192, 256, 0, stream>>>(x, xb);
  cvt_w1t<<<512, 256, 0, stream>>>(W1, w1t);
  cvt_w2t<<<128, 256, 0, stream>>>(W2, w2t);
  gemm1_fused<<<1024, 256, 0, stream>>>(xb, w1t, b1, w2t, Ep);
  vqc_final<<<1024, 256, 0, stream>>>(Ep, b2, vqc, Wd, bd, out);
}